// Round 4
// baseline (844.279 us; speedup 1.0000x reference)
//
#include <hip/hip_runtime.h>

// ---------------------------------------------------------------------------
// Sparse UNet forward — round 4: barrier-free direct-fragment gather MFMA,
//   max-parallelism edition. M_SUB=2 (128 rows/block), COUT split across
//   blockIdx.y (32 couts/block), deconv expressed as masked gather-MFMA.
// ---------------------------------------------------------------------------

#define EPS 1e-4f

typedef __attribute__((ext_vector_type(8))) short short8;   // 8 x bf16
typedef __attribute__((ext_vector_type(4))) float f32x4;

__device__ __forceinline__ unsigned short f2bf(float f) {
    union { float f; unsigned int u; } v; v.f = f;
    unsigned int r = v.u + 0x7fffu + ((v.u >> 16) & 1u);   // RNE
    return (unsigned short)(r >> 16);
}

__global__ void zero_kernel(float* p, int n) {
    int i = blockIdx.x * 256 + threadIdx.x;
    if (i < n) p[i] = 0.f;
}

// Per-channel sum / sumsq, atomically accumulated into stats[0:C], stats[C:2C].
template <int C>
__global__ __launch_bounds__(256) void bn_stats(const float* __restrict__ x,
                                                int rows, int stride,
                                                float* __restrict__ stats) {
    const int tid = threadIdx.x;
    const int c = tid & (C - 1);
    const int g = tid / C;
    const int GR = 256 / C;
    float s = 0.f, s2 = 0.f;
    for (int r = blockIdx.x * GR + g; r < rows; r += gridDim.x * GR) {
        float v = x[(size_t)r * stride + c];
        s += v; s2 += v * v;
    }
    __shared__ float sh[2][256];
    sh[0][tid] = s; sh[1][tid] = s2;
    __syncthreads();
    for (int off = 128; off >= C; off >>= 1) {
        if (tid < off) { sh[0][tid] += sh[0][tid + off]; sh[1][tid] += sh[1][tid + off]; }
        __syncthreads();
    }
    if (tid < C) {
        atomicAdd(&stats[c], sh[0][tid]);
        atomicAdd(&stats[C + c], sh[1][tid]);
    }
}

// BN finalize + ReLU -> bf16, 8 channels/thread. Output packed (rows+1) x C,
// sentinel row `rows` zeroed. Channel c stats from stA (c<CSPLIT) else stB.
template <int C, int CSPLIT>
__global__ __launch_bounds__(256) void bn_norm_relu_bf16(
    const float* __restrict__ x, int rows, int stride,
    const float* __restrict__ stA, const float* __restrict__ stB,
    const float* __restrict__ gamma, const float* __restrict__ beta,
    unsigned short* __restrict__ y) {
    constexpr int TPR = C / 8;
    int gid = blockIdx.x * 256 + threadIdx.x;
    int r = gid / TPR, t = gid % TPR;
    if (r > rows) return;
    short8 o8;
    if (r == rows) {
        for (int j = 0; j < 8; ++j) o8[j] = 0;
    } else {
        const float inv_n = 1.0f / (float)rows;
        const float* xr = x + (size_t)r * stride + t * 8;
        float4 v0 = *(const float4*)(xr);
        float4 v1 = *(const float4*)(xr + 4);
        float vv[8] = {v0.x, v0.y, v0.z, v0.w, v1.x, v1.y, v1.z, v1.w};
#pragma unroll
        for (int j = 0; j < 8; ++j) {
            int c = t * 8 + j;
            const float* st = (c < CSPLIT) ? stA : stB;
            int cc = (c < CSPLIT) ? c : c - CSPLIT;
            int cs = (c < CSPLIT) ? CSPLIT : (C - CSPLIT);
            float mu = st[cc] * inv_n;
            float var = st[cs + cc] * inv_n - mu * mu;
            float sc = gamma[c] * rsqrtf(var + EPS);
            float shf = beta[c] - mu * sc;
            float ov = fmaxf(0.f, fmaf(vv[j], sc, shf));
            o8[j] = (short)f2bf(ov);
        }
    }
    *(short8*)(y + (size_t)r * C + t * 8) = o8;
}

// W [K][CIN][COUT] f32 -> WT [K][COUT][CIN] bf16 (B-fragment friendly).
template <int CIN, int COUT>
__global__ void wt_transpose(const float* __restrict__ W, unsigned short* __restrict__ WT, int K) {
    int id = blockIdx.x * 256 + threadIdx.x;
    int total = K * CIN * COUT;
    if (id >= total) return;
    int t = id / (CIN * COUT);
    int r = id % (CIN * COUT);
    int co = r / CIN;
    int ci = r % CIN;
    WT[id] = f2bf(W[(size_t)t * CIN * COUT + ci * COUT + co]);
}

// nbr_up[k][i] = (up_k[i]==k) ? up_cidx[i] : sentinel M  -> deconv as conv.
__global__ void build_up_nbr(const int* __restrict__ up_cidx,
                             const int* __restrict__ up_k,
                             int* __restrict__ nbr_up, int Nrows, int M) {
    int i = blockIdx.x * 256 + threadIdx.x;
    if (i >= Nrows) return;
    int c = up_cidx[i];
    int k = up_k[i];
#pragma unroll
    for (int t = 0; t < 8; ++t)
        nbr_up[(size_t)t * Nrows + i] = (t == k) ? c : M;
}

// Barrier-free gather-GEMM, MFMA 16x16x32 bf16, direct fragment gather.
//   fpad: (P+1) x CIN bf16, row P zeros.  WT: [K][COT][CIN] bf16.
//   Block covers 128 rows (M_SUB=2 per wave, 4 waves) x 32 couts
//   (co0 = blockIdx.y*32). 2-stage register ping-pong over taps.
template <int CIN, int COT, int M_SUB>
__global__ __launch_bounds__(256) void conv_mfma_direct(
    const unsigned short* __restrict__ fpad,
    const int* __restrict__ nbr,
    const unsigned short* __restrict__ WT,
    float* __restrict__ out,
    int rows, int K, int P, int out_stride) {
    constexpr int N_SUB = 2;                 // 32 couts per block
    constexpr int K_SUB = CIN / 32;
    const int tid = threadIdx.x;
    const int wave = tid >> 6;
    const int lane = tid & 63;
    const int q = lane >> 4;
    const int l15 = lane & 15;
    const int m0 = blockIdx.x * (4 * M_SUB * 16) + wave * (M_SUB * 16);
    const int co0 = blockIdx.y * 32;

    f32x4 acc[M_SUB][N_SUB];
#pragma unroll
    for (int mt = 0; mt < M_SUB; ++mt)
#pragma unroll
        for (int nt = 0; nt < N_SUB; ++nt) acc[mt][nt] = (f32x4){0.f, 0.f, 0.f, 0.f};

    int idxA[M_SUB], idxB[M_SUB];
    short8 aA[M_SUB][K_SUB], aB[M_SUB][K_SUB];
    short8 bA[N_SUB][K_SUB], bB[N_SUB][K_SUB];

    auto load_idx = [&](int k, int (&dst)[M_SUB]) {
#pragma unroll
        for (int mt = 0; mt < M_SUB; ++mt) {
            int m = m0 + mt * 16 + l15;
            dst[mt] = (m < rows) ? nbr[(size_t)k * rows + m] : P;
        }
    };
    auto load_a = [&](const int (&src)[M_SUB], short8 (&dst)[M_SUB][K_SUB]) {
#pragma unroll
        for (int mt = 0; mt < M_SUB; ++mt)
#pragma unroll
            for (int kf = 0; kf < K_SUB; ++kf)
                dst[mt][kf] = *(const short8*)(fpad + (size_t)src[mt] * CIN + kf * 32 + q * 8);
    };
    auto load_b = [&](int k, short8 (&dst)[N_SUB][K_SUB]) {
        const unsigned short* Wk = WT + (size_t)k * COT * CIN;
#pragma unroll
        for (int nt = 0; nt < N_SUB; ++nt)
#pragma unroll
            for (int kf = 0; kf < K_SUB; ++kf)
                dst[nt][kf] = *(const short8*)(Wk + (size_t)(co0 + nt * 16 + l15) * CIN + kf * 32 + q * 8);
    };
    auto compute = [&](short8 (&a)[M_SUB][K_SUB], short8 (&b)[N_SUB][K_SUB]) {
#pragma unroll
        for (int mt = 0; mt < M_SUB; ++mt)
#pragma unroll
            for (int nt = 0; nt < N_SUB; ++nt)
#pragma unroll
                for (int kf = 0; kf < K_SUB; ++kf)
                    acc[mt][nt] = __builtin_amdgcn_mfma_f32_16x16x32_bf16(
                        a[mt][kf], b[nt][kf], acc[mt][nt], 0, 0, 0);
    };

    // Prologue: frags for tap 0 in set A; idxA = indices for tap 1.
    {
        int tmp[M_SUB];
        load_idx(0, tmp);
        load_a(tmp, aA);
        load_b(0, bA);
        if (K > 1) load_idx(1, idxA);
    }
    int k = 0;
    for (; k + 1 < K; k += 2) {
        load_a(idxA, aB);
        load_b(k + 1, bB);
        load_idx((k + 2 < K) ? k + 2 : 0, idxB);
        compute(aA, bA);
        if (k + 2 < K) {
            load_a(idxB, aA);
            load_b(k + 2, bA);
            load_idx((k + 3 < K) ? k + 3 : 0, idxA);
        }
        compute(aB, bB);
    }
    if (k < K) compute(aA, bA);   // odd K tail (tap K-1 staged in set A)

    // C/D layout: col = lane&15, row = q*4 + reg  [measured m89/m91]
#pragma unroll
    for (int mt = 0; mt < M_SUB; ++mt)
#pragma unroll
        for (int i = 0; i < 4; ++i) {
            int row = m0 + mt * 16 + q * 4 + i;
            if (row < rows) {
#pragma unroll
                for (int nt = 0; nt < N_SUB; ++nt)
                    out[(size_t)row * out_stride + co0 + nt * 16 + l15] = acc[mt][nt][i];
            }
        }
}

static inline int ceil_div(long a, long b) { return (int)((a + b - 1) / b); }

extern "C" void kernel_launch(void* const* d_in, const int* in_sizes, int n_in,
                              void* d_out, int out_size, void* d_ws, size_t ws_size,
                              hipStream_t stream) {
    const float* feat   = (const float*)d_in[0];
    const float* w_sub1 = (const float*)d_in[1];
    const float* w_down = (const float*)d_in[2];
    const float* w_sub2 = (const float*)d_in[3];
    const float* w_up   = (const float*)d_in[4];
    const float* w_sub3 = (const float*)d_in[5];
    const float* g1 = (const float*)d_in[6],  *b1 = (const float*)d_in[7];
    const float* g2 = (const float*)d_in[8],  *b2 = (const float*)d_in[9];
    const float* g3 = (const float*)d_in[10], *b3 = (const float*)d_in[11];
    const float* g4 = (const float*)d_in[12], *b4 = (const float*)d_in[13];
    const float* g5 = (const float*)d_in[14], *b5 = (const float*)d_in[15];
    const int* nbr_fine   = (const int*)d_in[16];
    const int* nbr_coarse = (const int*)d_in[17];
    const int* down_idx   = (const int*)d_in[18];
    const int* up_cidx    = (const int*)d_in[19];
    const int* up_k       = (const int*)d_in[20];

    const int N = in_sizes[0] / 32;
    const int M = in_sizes[17] / 27;
    const size_t maxr = (size_t)((N > M ? N : M) + 1);

    char* ws = (char*)d_ws;
    size_t off = 0;
    auto alloc = [&](size_t bytes) { void* p = ws + off; off += (bytes + 255) & ~(size_t)255; return p; };
    float* stats = (float*)alloc(6 * 128 * sizeof(float));
    float* D  = (float*)alloc((size_t)N * 64 * sizeof(float));        // concat buf [skip|up]
    float* Cf = (float*)alloc((size_t)M * 64 * sizeof(float));        // coarse f32 temp
    unsigned short* FA = (unsigned short*)alloc(maxr * 64 * 2);       // bf16 features A
    unsigned short* FB = (unsigned short*)alloc(maxr * 64 * 2);       // bf16 features B
    int* nbr_up = (int*)alloc((size_t)N * 8 * sizeof(int));
    unsigned short* w1t = (unsigned short*)alloc(27 * 32 * 32 * 2);
    unsigned short* wdt = (unsigned short*)alloc(8 * 32 * 64 * 2);
    unsigned short* w2t = (unsigned short*)alloc(27 * 64 * 64 * 2);
    unsigned short* w3t = (unsigned short*)alloc(27 * 64 * 32 * 2);
    unsigned short* wupT = (unsigned short*)alloc(8 * 64 * 32 * 2);

    float* st0 = stats + 0 * 128;
    float* st1 = stats + 1 * 128;
    float* st2 = stats + 2 * 128;
    float* st3 = stats + 3 * 128;
    float* st4 = stats + 4 * 128;   // deconv-half stats (32 ch) of concat

    zero_kernel<<<3, 256, 0, stream>>>(stats, 6 * 128);
    wt_transpose<32, 32><<<ceil_div(27 * 32 * 32, 256), 256, 0, stream>>>(w_sub1, w1t, 27);
    wt_transpose<32, 64><<<ceil_div(8 * 32 * 64, 256), 256, 0, stream>>>(w_down, wdt, 8);
    wt_transpose<64, 64><<<ceil_div(27 * 64 * 64, 256), 256, 0, stream>>>(w_sub2, w2t, 27);
    wt_transpose<64, 32><<<ceil_div(27 * 64 * 32, 256), 256, 0, stream>>>(w_sub3, w3t, 27);
    wt_transpose<64, 32><<<ceil_div(8 * 64 * 32, 256), 256, 0, stream>>>(w_up, wupT, 8);
    build_up_nbr<<<ceil_div(N, 256), 256, 0, stream>>>(up_cidx, up_k, nbr_up, N, M);

    // 1) BN0+ReLU(feat) -> FA [(N+1)x32 bf16]
    bn_stats<32><<<256, 256, 0, stream>>>(feat, N, 32, st0);
    bn_norm_relu_bf16<32, 32><<<ceil_div((long)(N + 1) * 4, 256), 256, 0, stream>>>(
        feat, N, 32, st0, st0, g1, b1, FA);
    // 2) conv1 (27, 32->32): FA -> D[:,0:32] (skip); 128 rows/block
    conv_mfma_direct<32, 32, 2><<<dim3(ceil_div(N, 128), 1), 256, 0, stream>>>(
        FA, nbr_fine, w1t, D, N, 27, N, 64);
    // 3) BN1+ReLU(skip) -> FB [(N+1)x32]
    bn_stats<32><<<256, 256, 0, stream>>>(D, N, 64, st1);
    bn_norm_relu_bf16<32, 32><<<ceil_div((long)(N + 1) * 4, 256), 256, 0, stream>>>(
        D, N, 64, st1, st1, g2, b2, FB);
    // 4) down conv (8, 32->64): FB -> Cf; cout-split x2
    conv_mfma_direct<32, 64, 2><<<dim3(ceil_div(M, 128), 2), 256, 0, stream>>>(
        FB, down_idx, wdt, Cf, M, 8, N, 64);
    // 5) BN2+ReLU(Cf) -> FA [(M+1)x64]
    bn_stats<64><<<256, 256, 0, stream>>>(Cf, M, 64, st2);
    bn_norm_relu_bf16<64, 64><<<ceil_div((long)(M + 1) * 8, 256), 256, 0, stream>>>(
        Cf, M, 64, st2, st2, g3, b3, FA);
    // 6) conv2 (27, 64->64): FA -> Cf; cout-split x2
    conv_mfma_direct<64, 64, 2><<<dim3(ceil_div(M, 128), 2), 256, 0, stream>>>(
        FA, nbr_coarse, w2t, Cf, M, 27, M, 64);
    // 7) BN3+ReLU(Cf) -> FB [(M+1)x64]
    bn_stats<64><<<256, 256, 0, stream>>>(Cf, M, 64, st3);
    bn_norm_relu_bf16<64, 64><<<ceil_div((long)(M + 1) * 8, 256), 256, 0, stream>>>(
        Cf, M, 64, st3, st3, g4, b4, FB);
    // 8) deconv (64->32) as masked gather-conv (K=8): FB -> D[:,32:64]
    conv_mfma_direct<64, 32, 2><<<dim3(ceil_div(N, 128), 1), 256, 0, stream>>>(
        FB, nbr_up, wupT, D + 32, N, 8, M, 64);
    // 9) BN4+ReLU(D) -> FA [(N+1)x64]; low 32 ch stats == st1, high 32 = st4
    bn_stats<32><<<256, 256, 0, stream>>>(D + 32, N, 64, st4);
    bn_norm_relu_bf16<64, 32><<<ceil_div((long)(N + 1) * 8, 256), 256, 0, stream>>>(
        D, N, 64, st1, st4, g5, b5, FA);
    // 10) conv3 (27, 64->32): FA -> d_out
    conv_mfma_direct<64, 32, 2><<<dim3(ceil_div(N, 128), 1), 256, 0, stream>>>(
        FA, nbr_fine, w3t, (float*)d_out, N, 27, N, 32);
}

// Round 5
// 734.341 us; speedup vs baseline: 1.1497x; 1.1497x over previous
//
#include <hip/hip_runtime.h>

// ---------------------------------------------------------------------------
// Sparse UNet forward — round 5: barrier-free gather MFMA
//   + XCD-contiguous block swizzle (L2 locality for gathers)
//   + full-COUT blocks (no cout split — halves A traffic)
//   + BN stats fused into conv epilogue (drops 4 bn_stats passes)
// ---------------------------------------------------------------------------

#define EPS 1e-4f

typedef __attribute__((ext_vector_type(8))) short short8;   // 8 x bf16
typedef __attribute__((ext_vector_type(4))) float f32x4;

__device__ __forceinline__ unsigned short f2bf(float f) {
    union { float f; unsigned int u; } v; v.f = f;
    unsigned int r = v.u + 0x7fffu + ((v.u >> 16) & 1u);   // RNE
    return (unsigned short)(r >> 16);
}

__global__ void zero_kernel(float* p, int n) {
    int i = blockIdx.x * 256 + threadIdx.x;
    if (i < n) p[i] = 0.f;
}

// Per-channel sum / sumsq (only used for the input feature BN).
template <int C>
__global__ __launch_bounds__(256) void bn_stats(const float* __restrict__ x,
                                                int rows, int stride,
                                                float* __restrict__ stats) {
    const int tid = threadIdx.x;
    const int c = tid & (C - 1);
    const int g = tid / C;
    const int GR = 256 / C;
    float s = 0.f, s2 = 0.f;
    for (int r = blockIdx.x * GR + g; r < rows; r += gridDim.x * GR) {
        float v = x[(size_t)r * stride + c];
        s += v; s2 += v * v;
    }
    __shared__ float sh[2][256];
    sh[0][tid] = s; sh[1][tid] = s2;
    __syncthreads();
    for (int off = 128; off >= C; off >>= 1) {
        if (tid < off) { sh[0][tid] += sh[0][tid + off]; sh[1][tid] += sh[1][tid + off]; }
        __syncthreads();
    }
    if (tid < C) {
        atomicAdd(&stats[c], sh[0][tid]);
        atomicAdd(&stats[C + c], sh[1][tid]);
    }
}

// BN finalize + ReLU -> bf16, 8 channels/thread. Output packed (rows+1) x C,
// sentinel row `rows` zeroed. Channel c stats from stA (c<CSPLIT) else stB.
template <int C, int CSPLIT>
__global__ __launch_bounds__(256) void bn_norm_relu_bf16(
    const float* __restrict__ x, int rows, int stride,
    const float* __restrict__ stA, const float* __restrict__ stB,
    const float* __restrict__ gamma, const float* __restrict__ beta,
    unsigned short* __restrict__ y) {
    constexpr int TPR = C / 8;
    int gid = blockIdx.x * 256 + threadIdx.x;
    int r = gid / TPR, t = gid % TPR;
    if (r > rows) return;
    short8 o8;
    if (r == rows) {
        for (int j = 0; j < 8; ++j) o8[j] = 0;
    } else {
        const float inv_n = 1.0f / (float)rows;
        const float* xr = x + (size_t)r * stride + t * 8;
        float4 v0 = *(const float4*)(xr);
        float4 v1 = *(const float4*)(xr + 4);
        float vv[8] = {v0.x, v0.y, v0.z, v0.w, v1.x, v1.y, v1.z, v1.w};
#pragma unroll
        for (int j = 0; j < 8; ++j) {
            int c = t * 8 + j;
            const float* st = (c < CSPLIT) ? stA : stB;
            int cc = (c < CSPLIT) ? c : c - CSPLIT;
            int cs = (c < CSPLIT) ? CSPLIT : (C - CSPLIT);
            float mu = st[cc] * inv_n;
            float var = st[cs + cc] * inv_n - mu * mu;
            float sc = gamma[c] * rsqrtf(var + EPS);
            float shf = beta[c] - mu * sc;
            float ov = fmaxf(0.f, fmaf(vv[j], sc, shf));
            o8[j] = (short)f2bf(ov);
        }
    }
    *(short8*)(y + (size_t)r * C + t * 8) = o8;
}

// W [K][CIN][COUT] f32 -> WT [K][COUT][CIN] bf16 (B-fragment friendly).
template <int CIN, int COUT>
__global__ void wt_transpose(const float* __restrict__ W, unsigned short* __restrict__ WT, int K) {
    int id = blockIdx.x * 256 + threadIdx.x;
    int total = K * CIN * COUT;
    if (id >= total) return;
    int t = id / (CIN * COUT);
    int r = id % (CIN * COUT);
    int co = r / CIN;
    int ci = r % CIN;
    WT[id] = f2bf(W[(size_t)t * CIN * COUT + ci * COUT + co]);
}

// nbr_up[k][i] = (up_k[i]==k) ? up_cidx[i] : sentinel M  -> deconv as conv.
__global__ void build_up_nbr(const int* __restrict__ up_cidx,
                             const int* __restrict__ up_k,
                             int* __restrict__ nbr_up, int Nrows, int M) {
    int i = blockIdx.x * 256 + threadIdx.x;
    if (i >= Nrows) return;
    int c = up_cidx[i];
    int k = up_k[i];
#pragma unroll
    for (int t = 0; t < 8; ++t)
        nbr_up[(size_t)t * Nrows + i] = (t == k) ? c : M;
}

// Barrier-free gather-GEMM, MFMA 16x16x32 bf16, direct fragment gather.
//   fpad: (P+1) x CIN bf16, row P zeros.  WT: [K][COT][CIN] bf16.
//   Block covers 128 rows (M_SUB=2/wave, 4 waves) x COT couts.
//   XCD-contiguous swizzle: gridDim.x is a multiple of 8; hardware block
//   b -> logical block (b&7)*(nb/8) + (b>>3) so each XCD owns a contiguous
//   z-order row range (gather working set fits its private 4 MiB L2).
//   If stats != nullptr: per-channel sum/sumsq of the output tile is reduced
//   (shfl over q + LDS) and atomically added to stats[0:COT], stats[COT:2COT].
template <int CIN, int COT, int M_SUB>
__global__ __launch_bounds__(256) void conv_mfma_direct(
    const unsigned short* __restrict__ fpad,
    const int* __restrict__ nbr,
    const unsigned short* __restrict__ WT,
    float* __restrict__ out,
    float* __restrict__ stats,
    int rows, int K, int P, int out_stride) {
    constexpr int N_SUB = COT / 16;
    constexpr int K_SUB = CIN / 32;
    constexpr int TILE = 4 * M_SUB * 16;
    const int tid = threadIdx.x;
    const int wave = tid >> 6;
    const int lane = tid & 63;
    const int q = lane >> 4;
    const int l15 = lane & 15;

    const int nb = gridDim.x;                 // multiple of 8
    const int b = blockIdx.x;
    const int bl = (b & 7) * (nb >> 3) + (b >> 3);
    if (bl * TILE >= rows) return;            // padded block, no work (uniform)
    const int m0 = bl * TILE + wave * (M_SUB * 16);

    f32x4 acc[M_SUB][N_SUB];
#pragma unroll
    for (int mt = 0; mt < M_SUB; ++mt)
#pragma unroll
        for (int nt = 0; nt < N_SUB; ++nt) acc[mt][nt] = (f32x4){0.f, 0.f, 0.f, 0.f};

    int idxA[M_SUB], idxB[M_SUB];
    short8 aA[M_SUB][K_SUB], aB[M_SUB][K_SUB];
    short8 bA[N_SUB][K_SUB], bB[N_SUB][K_SUB];

    auto load_idx = [&](int k, int (&dst)[M_SUB]) {
#pragma unroll
        for (int mt = 0; mt < M_SUB; ++mt) {
            int m = m0 + mt * 16 + l15;
            dst[mt] = (m < rows) ? nbr[(size_t)k * rows + m] : P;
        }
    };
    auto load_a = [&](const int (&src)[M_SUB], short8 (&dst)[M_SUB][K_SUB]) {
#pragma unroll
        for (int mt = 0; mt < M_SUB; ++mt)
#pragma unroll
            for (int kf = 0; kf < K_SUB; ++kf)
                dst[mt][kf] = *(const short8*)(fpad + (size_t)src[mt] * CIN + kf * 32 + q * 8);
    };
    auto load_b = [&](int k, short8 (&dst)[N_SUB][K_SUB]) {
        const unsigned short* Wk = WT + (size_t)k * COT * CIN;
#pragma unroll
        for (int nt = 0; nt < N_SUB; ++nt)
#pragma unroll
            for (int kf = 0; kf < K_SUB; ++kf)
                dst[nt][kf] = *(const short8*)(Wk + (size_t)(nt * 16 + l15) * CIN + kf * 32 + q * 8);
    };
    auto compute = [&](short8 (&a)[M_SUB][K_SUB], short8 (&b_)[N_SUB][K_SUB]) {
#pragma unroll
        for (int mt = 0; mt < M_SUB; ++mt)
#pragma unroll
            for (int nt = 0; nt < N_SUB; ++nt)
#pragma unroll
                for (int kf = 0; kf < K_SUB; ++kf)
                    acc[mt][nt] = __builtin_amdgcn_mfma_f32_16x16x32_bf16(
                        a[mt][kf], b_[nt][kf], acc[mt][nt], 0, 0, 0);
    };

    // Prologue: frags for tap 0 in set A; idxA = indices for tap 1.
    {
        int tmp[M_SUB];
        load_idx(0, tmp);
        load_a(tmp, aA);
        load_b(0, bA);
        if (K > 1) load_idx(1, idxA);
    }
    int k = 0;
    for (; k + 1 < K; k += 2) {
        load_a(idxA, aB);
        load_b(k + 1, bB);
        load_idx((k + 2 < K) ? k + 2 : 0, idxB);
        compute(aA, bA);
        if (k + 2 < K) {
            load_a(idxB, aA);
            load_b(k + 2, bA);
            load_idx((k + 3 < K) ? k + 3 : 0, idxA);
        }
        compute(aB, bB);
    }
    if (k < K) compute(aA, bA);   // odd K tail (tap K-1 staged in set A)

    // C/D layout: col = lane&15, row = q*4 + reg  [measured m89/m91]
#pragma unroll
    for (int mt = 0; mt < M_SUB; ++mt)
#pragma unroll
        for (int i = 0; i < 4; ++i) {
            int row = m0 + mt * 16 + q * 4 + i;
            if (row < rows) {
#pragma unroll
                for (int nt = 0; nt < N_SUB; ++nt)
                    out[(size_t)row * out_stride + nt * 16 + l15] = acc[mt][nt][i];
            }
        }

    // Fused BN statistics: OOB rows hold acc==0 (sentinel gathers) -> no mask.
    if (stats) {
        __shared__ float ssum[COT], ssq[COT];
        for (int i = tid; i < 2 * COT; i += 256)
            (i < COT ? ssum[i] : ssq[i - COT]) = 0.f;
        __syncthreads();
#pragma unroll
        for (int nt = 0; nt < N_SUB; ++nt) {
            float s = 0.f, s2 = 0.f;
#pragma unroll
            for (int mt = 0; mt < M_SUB; ++mt)
#pragma unroll
                for (int i = 0; i < 4; ++i) {
                    float v = acc[mt][nt][i];
                    s += v; s2 += v * v;
                }
            s += __shfl_xor(s, 16);  s += __shfl_xor(s, 32);
            s2 += __shfl_xor(s2, 16); s2 += __shfl_xor(s2, 32);
            if (q == 0) {
                atomicAdd(&ssum[nt * 16 + l15], s);
                atomicAdd(&ssq[nt * 16 + l15], s2);
            }
        }
        __syncthreads();
        if (tid < COT) {
            atomicAdd(&stats[tid], ssum[tid]);
            atomicAdd(&stats[COT + tid], ssq[tid]);
        }
    }
}

static inline int ceil_div(long a, long b) { return (int)((a + b - 1) / b); }
static inline int pad8(int g) { return ((g + 7) / 8) * 8; }

extern "C" void kernel_launch(void* const* d_in, const int* in_sizes, int n_in,
                              void* d_out, int out_size, void* d_ws, size_t ws_size,
                              hipStream_t stream) {
    const float* feat   = (const float*)d_in[0];
    const float* w_sub1 = (const float*)d_in[1];
    const float* w_down = (const float*)d_in[2];
    const float* w_sub2 = (const float*)d_in[3];
    const float* w_up   = (const float*)d_in[4];
    const float* w_sub3 = (const float*)d_in[5];
    const float* g1 = (const float*)d_in[6],  *b1 = (const float*)d_in[7];
    const float* g2 = (const float*)d_in[8],  *b2 = (const float*)d_in[9];
    const float* g3 = (const float*)d_in[10], *b3 = (const float*)d_in[11];
    const float* g4 = (const float*)d_in[12], *b4 = (const float*)d_in[13];
    const float* g5 = (const float*)d_in[14], *b5 = (const float*)d_in[15];
    const int* nbr_fine   = (const int*)d_in[16];
    const int* nbr_coarse = (const int*)d_in[17];
    const int* down_idx   = (const int*)d_in[18];
    const int* up_cidx    = (const int*)d_in[19];
    const int* up_k       = (const int*)d_in[20];

    const int N = in_sizes[0] / 32;
    const int M = in_sizes[17] / 27;
    const size_t maxr = (size_t)((N > M ? N : M) + 1);

    char* ws = (char*)d_ws;
    size_t off = 0;
    auto alloc = [&](size_t bytes) { void* p = ws + off; off += (bytes + 255) & ~(size_t)255; return p; };
    float* stats = (float*)alloc(6 * 128 * sizeof(float));
    float* D  = (float*)alloc((size_t)N * 64 * sizeof(float));        // concat buf [skip|up]
    float* Cf = (float*)alloc((size_t)M * 64 * sizeof(float));        // coarse f32 temp
    unsigned short* FA = (unsigned short*)alloc(maxr * 64 * 2);       // bf16 features A
    unsigned short* FB = (unsigned short*)alloc(maxr * 64 * 2);       // bf16 features B
    int* nbr_up = (int*)alloc((size_t)N * 8 * sizeof(int));
    unsigned short* w1t = (unsigned short*)alloc(27 * 32 * 32 * 2);
    unsigned short* wdt = (unsigned short*)alloc(8 * 32 * 64 * 2);
    unsigned short* w2t = (unsigned short*)alloc(27 * 64 * 64 * 2);
    unsigned short* w3t = (unsigned short*)alloc(27 * 64 * 32 * 2);
    unsigned short* wupT = (unsigned short*)alloc(8 * 64 * 32 * 2);

    float* st0 = stats + 0 * 128;
    float* st1 = stats + 1 * 128;   // conv1 out (32 ch)
    float* st2 = stats + 2 * 128;   // down out (64 ch)
    float* st3 = stats + 3 * 128;   // conv2 out (64 ch)
    float* st4 = stats + 4 * 128;   // deconv out (32 ch)

    zero_kernel<<<3, 256, 0, stream>>>(stats, 6 * 128);
    wt_transpose<32, 32><<<ceil_div(27 * 32 * 32, 256), 256, 0, stream>>>(w_sub1, w1t, 27);
    wt_transpose<32, 64><<<ceil_div(8 * 32 * 64, 256), 256, 0, stream>>>(w_down, wdt, 8);
    wt_transpose<64, 64><<<ceil_div(27 * 64 * 64, 256), 256, 0, stream>>>(w_sub2, w2t, 27);
    wt_transpose<64, 32><<<ceil_div(27 * 64 * 32, 256), 256, 0, stream>>>(w_sub3, w3t, 27);
    wt_transpose<64, 32><<<ceil_div(8 * 64 * 32, 256), 256, 0, stream>>>(w_up, wupT, 8);
    build_up_nbr<<<ceil_div(N, 256), 256, 0, stream>>>(up_cidx, up_k, nbr_up, N, M);

    // 1) BN0+ReLU(feat) -> FA [(N+1)x32 bf16]
    bn_stats<32><<<256, 256, 0, stream>>>(feat, N, 32, st0);
    bn_norm_relu_bf16<32, 32><<<ceil_div((long)(N + 1) * 4, 256), 256, 0, stream>>>(
        feat, N, 32, st0, st0, g1, b1, FA);
    // 2) conv1 (27, 32->32): FA -> D[:,0:32]; fused stats -> st1
    conv_mfma_direct<32, 32, 2><<<pad8(ceil_div(N, 128)), 256, 0, stream>>>(
        FA, nbr_fine, w1t, D, st1, N, 27, N, 64);
    // 3) BN1+ReLU(skip) -> FB [(N+1)x32]
    bn_norm_relu_bf16<32, 32><<<ceil_div((long)(N + 1) * 4, 256), 256, 0, stream>>>(
        D, N, 64, st1, st1, g2, b2, FB);
    // 4) down conv (8, 32->64): FB -> Cf; fused stats -> st2
    conv_mfma_direct<32, 64, 2><<<pad8(ceil_div(M, 128)), 256, 0, stream>>>(
        FB, down_idx, wdt, Cf, st2, M, 8, N, 64);
    // 5) BN2+ReLU(Cf) -> FA [(M+1)x64]
    bn_norm_relu_bf16<64, 64><<<ceil_div((long)(M + 1) * 8, 256), 256, 0, stream>>>(
        Cf, M, 64, st2, st2, g3, b3, FA);
    // 6) conv2 (27, 64->64): FA -> Cf; fused stats -> st3
    conv_mfma_direct<64, 64, 2><<<pad8(ceil_div(M, 128)), 256, 0, stream>>>(
        FA, nbr_coarse, w2t, Cf, st3, M, 27, M, 64);
    // 7) BN3+ReLU(Cf) -> FB [(M+1)x64]
    bn_norm_relu_bf16<64, 64><<<ceil_div((long)(M + 1) * 8, 256), 256, 0, stream>>>(
        Cf, M, 64, st3, st3, g4, b4, FB);
    // 8) deconv (64->32) as masked gather-conv (K=8): FB -> D[:,32:64]; stats -> st4
    conv_mfma_direct<64, 32, 2><<<pad8(ceil_div(N, 128)), 256, 0, stream>>>(
        FB, nbr_up, wupT, D + 32, st4, N, 8, M, 64);
    // 9) BN4+ReLU(D) -> FA [(N+1)x64]; low 32 ch stats = st1, high 32 = st4
    bn_norm_relu_bf16<64, 32><<<ceil_div((long)(N + 1) * 8, 256), 256, 0, stream>>>(
        D, N, 64, st1, st4, g5, b5, FA);
    // 10) conv3 (27, 64->32): FA -> d_out (no following BN)
    conv_mfma_direct<64, 32, 2><<<pad8(ceil_div(N, 128)), 256, 0, stream>>>(
        FA, nbr_fine, w3t, (float*)d_out, nullptr, N, 27, N, 32);
}